// Round 11
// baseline (156.594 us; speedup 1.0000x reference)
//
#include <hip/hip_runtime.h>
#include <hip/hip_bf16.h>

#define Bsz 4
#define Ssz 2048
#define Dsz 512
#define Hsz 8
#define DKsz 64

typedef __bf16 bf16x8 __attribute__((ext_vector_type(8)));
typedef __bf16 bf16x4 __attribute__((ext_vector_type(4)));
typedef float f32x4 __attribute__((ext_vector_type(4)));

// chunk-swizzled element offset: 16B chunk c of a 64-elem (128B) row, XOR row&7
#define SWE(c, row) ((((c) ^ ((row) & 7)) * 8))

// ---------------------------------------------------------------------------
// cvt: x (4.19M fp32) + Wq|Wk|Wv (3 x 262144 fp32) -> bf16 in ws.
__global__ __launch_bounds__(256) void cvt_kernel(
    const float* __restrict__ x, const float* __restrict__ Wq,
    const float* __restrict__ Wk, const float* __restrict__ Wv,
    __bf16* __restrict__ xb, __bf16* __restrict__ Wb)
{
    const int i = blockIdx.x * 256 + threadIdx.x;   // float4 index
    const int XN4 = (Bsz * Ssz * Dsz) / 4;          // 1,048,576
    const float* src;
    __bf16* dst;
    int off;
    if (i < XN4) {
        src = x; dst = xb; off = i;
    } else {
        int j = i - XN4;                             // 0 .. 196607
        int w = j >> 16;                             // 0,1,2
        off = j & 65535;
        src = (w == 0) ? Wq : (w == 1) ? Wk : Wv;
        dst = Wb + (size_t)w * (Dsz * Dsz);
    }
    float4 v = ((const float4*)src)[off];
    __bf16 o[4] = {(__bf16)v.x, (__bf16)v.y, (__bf16)v.z, (__bf16)v.w};
    *(uint2*)(dst + (size_t)off * 4) = *(uint2*)o;
}

// ---------------------------------------------------------------------------
// Fused qkv projection (R9 structure: bf16 inputs via cvt). L2-locality grid
// (1-D, 768 blocks): XCD = lin&7; 12 time-adjacent blocks per XCD share one
// x-tile and sweep all 12 (tn,which) W-tiles. 128x128 tile, swizzled LDS,
// reg prefetch, packed 8B stores.
// which<2 (Q/K): C = W-tile x x-tile -> rows=e (in-lane), cols=s.
// which==2 (V) : C = x-tile x W-tile -> rows=s (in-lane), cols=e -> V^T.
__global__ __launch_bounds__(256, 3) void qkv_kernel(
    const __bf16* __restrict__ xb, const __bf16* __restrict__ Wb,
    __bf16* __restrict__ Qo, __bf16* __restrict__ Ko, __bf16* __restrict__ Vo)
{
    __shared__ __bf16 xs[128][64];
    __shared__ __bf16 wsh[128][64];

    const int tid  = threadIdx.x;
    const int lane = tid & 63;
    const int wave = tid >> 6;
    const int quad = lane >> 4;
    const int l16  = lane & 15;
    const int wm   = (wave & 1) * 64;
    const int wn   = (wave >> 1) * 64;

    const int lin = blockIdx.x;
    const int xcd = lin & 7;
    const int idx = lin >> 3;             // 0..95
    const int tnw = idx % 12;             // fast per XCD: sweeps (tn, which)
    const int tmh = idx / 12;             // slow: x-tile group
    const int tm  = (tmh * 8 + xcd) * 128;
    const int tn  = (tnw & 3) * 128;
    const int which = tnw >> 2;           // 0=Q 1=K 2=V
    const bool VM = (which == 2);
    const __bf16* W = Wb + (size_t)which * (Dsz * Dsz);

    const int srow = tid >> 3;            // 0..31 (+32i covers 128 rows)
    const int sc   = tid & 7;             // 16B chunk within the 128B row
    const int swz  = SWE(sc, srow);       // (srow+32i)&7 == srow&7: i-invariant

    const __bf16* xg = xb + (size_t)(tm + srow) * Dsz + sc * 8;
    const __bf16* wg = W  + (size_t)(tn + srow) * Dsz + sc * 8;

    bf16x8 px[4], pw[4];
    #pragma unroll
    for (int i = 0; i < 4; ++i) {
        px[i] = *(const bf16x8*)(xg + (size_t)(32 * i) * Dsz);
        pw[i] = *(const bf16x8*)(wg + (size_t)(32 * i) * Dsz);
    }

    f32x4 acc[4][4];
    #pragma unroll
    for (int i = 0; i < 4; ++i)
        #pragma unroll
        for (int j = 0; j < 4; ++j) acc[i][j] = (f32x4){0.f, 0.f, 0.f, 0.f};

    const __bf16 (*Ash)[64] = VM ? xs : wsh;
    const __bf16 (*Bsh)[64] = VM ? wsh : xs;

    for (int k0 = 0; k0 < Dsz; k0 += 64) {
        __syncthreads();
        #pragma unroll
        for (int i = 0; i < 4; ++i) {
            *(bf16x8*)&xs[srow + 32 * i][swz]  = px[i];
            *(bf16x8*)&wsh[srow + 32 * i][swz] = pw[i];
        }
        __syncthreads();
        if (k0 + 64 < Dsz) {
            #pragma unroll
            for (int i = 0; i < 4; ++i) {
                px[i] = *(const bf16x8*)(xg + (size_t)(32 * i) * Dsz + k0 + 64);
                pw[i] = *(const bf16x8*)(wg + (size_t)(32 * i) * Dsz + k0 + 64);
            }
        }

        #pragma unroll
        for (int kk = 0; kk < 2; ++kk) {
            bf16x8 fa[4], fb[4];
            #pragma unroll
            for (int mi = 0; mi < 4; ++mi) {
                const int row = wm + mi * 16 + l16;
                fa[mi] = *(const bf16x8*)&Ash[row][SWE(kk * 4 + quad, row)];
            }
            #pragma unroll
            for (int ni = 0; ni < 4; ++ni) {
                const int row = wn + ni * 16 + l16;
                fb[ni] = *(const bf16x8*)&Bsh[row][SWE(kk * 4 + quad, row)];
            }
            #pragma unroll
            for (int mi = 0; mi < 4; ++mi)
                #pragma unroll
                for (int ni = 0; ni < 4; ++ni)
                    acc[mi][ni] = __builtin_amdgcn_mfma_f32_16x16x32_bf16(
                        fa[mi], fb[ni], acc[mi][ni], 0, 0, 0);
        }
    }

    if (!VM) {
        const float scale = (which == 0) ? 0.125f * 1.44269504088896340736f : 1.0f;
        __bf16* dst = (which == 0) ? Qo : Ko;
        // rows = e (W-dim), in-lane regs r span 4 consecutive e -> 4 consecutive d
        #pragma unroll
        for (int mi = 0; mi < 4; ++mi) {
            const int e0 = tn + wm + mi * 16 + quad * 4;
            const int h = e0 >> 6, d0 = e0 & 63;
            #pragma unroll
            for (int ni = 0; ni < 4; ++ni) {
                const int sf = tm + wn + ni * 16 + l16;
                const int b = sf >> 11, s = sf & (Ssz - 1);
                bf16x4 p;
                #pragma unroll
                for (int r = 0; r < 4; ++r) p[r] = (__bf16)(acc[mi][ni][r] * scale);
                *(bf16x4*)&dst[((((size_t)(b * Hsz + h) * Ssz + s)) << 6) + d0] = p;
            }
        }
    } else {
        // rows = s, in-lane regs r span 4 consecutive s -> V^T packed stores
        #pragma unroll
        for (int mi = 0; mi < 4; ++mi) {
            const int sf0 = tm + wm + mi * 16 + quad * 4;
            const int b = sf0 >> 11, s0 = sf0 & (Ssz - 1);
            #pragma unroll
            for (int ni = 0; ni < 4; ++ni) {
                const int e = tn + wn + ni * 16 + l16;
                const int h = e >> 6, d = e & 63;
                bf16x4 p;
                #pragma unroll
                for (int r = 0; r < 4; ++r) p[r] = (__bf16)acc[mi][ni][r];
                *(bf16x4*)&Vo[(((size_t)(b * Hsz + h) * DKsz + d) << 11) + s0] = p;
            }
        }
    }
}

// ---------------------------------------------------------------------------
// Flash attention v2: 128-thread blocks (2 waves), qs=4 (64 q-rows/wave, 128
// q-rows/block), 4 blocks/CU. Frag reads amortize over 2x q-work -> 29% less
// LDS traffic than the 4-wave/qs=2 shape; barriers couple only 2 waves.
// S^T (A=K,B=Q) -> P^T b64 LDS writes; PV swapped (A=V^T,B=P^T) -> O^T regs
// -> f32x4 stores; row-sums via ones-MFMA (per-lane, col=q=l16).
__global__ __launch_bounds__(128, 2) void attn_kernel(
    const __bf16* __restrict__ Q, const __bf16* __restrict__ K,
    const __bf16* __restrict__ VT, float* __restrict__ out)
{
    __shared__ __bf16 ks[64][64];        // K[s_local][dk], swizzled chunks
    __shared__ __bf16 vs[64][64];        // V^T[dk][s_local], swizzled chunks
    __shared__ __bf16 ps[2][16][64];     // per-wave P^T buffer [q][s], swizzled

    const int tid  = threadIdx.x;
    const int lane = tid & 63;
    const int wave = tid >> 6;           // 0..1
    const int quad = lane >> 4;
    const int l16  = lane & 15;

    const int bh = blockIdx.x;           // all q-blocks of a bh share an XCD L2
    const int qt = blockIdx.y;           // 128-row q tile
    const int b  = bh >> 3;
    const int h  = bh & 7;

    const __bf16* Qb = Q  + (size_t)bh * Ssz * DKsz;
    const __bf16* Kb = K  + (size_t)bh * Ssz * DKsz;
    const __bf16* Vb = VT + (size_t)bh * DKsz * Ssz;

    // Q fragments: lane l16 = q-local row, quad*8 = dk chunk
    bf16x8 qf[4][2];
    #pragma unroll
    for (int qs = 0; qs < 4; ++qs) {
        const __bf16* qrow = Qb + (size_t)(qt * 128 + wave * 64 + qs * 16 + l16) * DKsz;
        qf[qs][0] = *(const bf16x8*)(qrow + quad * 8);
        qf[qs][1] = *(const bf16x8*)(qrow + 32 + quad * 8);
    }

    bf16x8 ones;
    #pragma unroll
    for (int i = 0; i < 8; ++i) ones[i] = (__bf16)1.0f;

    f32x4 oacc[4][4];
    #pragma unroll
    for (int qs = 0; qs < 4; ++qs)
        #pragma unroll
        for (int i = 0; i < 4; ++i) oacc[qs][i] = (f32x4){0.f, 0.f, 0.f, 0.f};
    f32x4 lacc[4];
    #pragma unroll
    for (int qs = 0; qs < 4; ++qs) lacc[qs] = (f32x4){0.f, 0.f, 0.f, 0.f};

    const int srow = tid >> 3;           // 0..15 (+16i covers 64 rows)
    const int sc   = tid & 7;            // 16B chunk within the 128B row
    const int swz  = SWE(sc, srow);      // (srow+16i)&7 == srow&7

    const __bf16* kg = Kb + (size_t)srow * DKsz + sc * 8;   // K rows = 128B
    const __bf16* vg = Vb + (size_t)srow * Ssz + sc * 8;    // V^T kb-slice

    bf16x8 pk[4], pv[4];
    #pragma unroll
    for (int i = 0; i < 4; ++i) {
        pk[i] = *(const bf16x8*)(kg + (size_t)(16 * i) * DKsz);
        pv[i] = *(const bf16x8*)(vg + (size_t)(16 * i) * Ssz);
    }

    for (int kb = 0; kb < Ssz; kb += 64) {
        __syncthreads();                 // previous tile fully consumed
        #pragma unroll
        for (int i = 0; i < 4; ++i) {
            *(bf16x8*)&ks[srow + 16 * i][swz] = pk[i];
            *(bf16x8*)&vs[srow + 16 * i][swz] = pv[i];
        }
        __syncthreads();

        if (kb + 64 < Ssz) {             // prefetch next K/V tile into regs
            #pragma unroll
            for (int i = 0; i < 4; ++i) {
                pk[i] = *(const bf16x8*)(kg + (size_t)(kb + 64 + 16 * i) * DKsz);
                pv[i] = *(const bf16x8*)(vg + (size_t)(16 * i) * Ssz + kb + 64);
            }
        }

        // read K and V tiles from LDS once into registers
        bf16x8 kf[2][4], vf[2][4];
        #pragma unroll
        for (int kk = 0; kk < 2; ++kk)
            #pragma unroll
            for (int ns = 0; ns < 4; ++ns) {
                const int row = ns * 16 + l16;
                kf[kk][ns] = *(const bf16x8*)&ks[row][SWE(kk * 4 + quad, row)];
                vf[kk][ns] = *(const bf16x8*)&vs[row][SWE(kk * 4 + quad, row)];
            }

        #pragma unroll
        for (int qs = 0; qs < 4; ++qs) {
            // S^T = K Q^T (C: row = s-local = ns*16+quad*4+r, col = q = l16)
            #pragma unroll
            for (int ns = 0; ns < 4; ++ns) {
                f32x4 st = (f32x4){0.f, 0.f, 0.f, 0.f};
                st = __builtin_amdgcn_mfma_f32_16x16x32_bf16(kf[0][ns], qf[qs][0], st, 0, 0, 0);
                st = __builtin_amdgcn_mfma_f32_16x16x32_bf16(kf[1][ns], qf[qs][1], st, 0, 0, 0);
                // P^T pack: 4 regs = 4 consecutive s for q=l16 -> one b64 write
                bf16x4 pp;
                #pragma unroll
                for (int r = 0; r < 4; ++r)
                    pp[r] = (__bf16)__builtin_amdgcn_exp2f(st[r]);
                const int c = ns * 2 + (quad >> 1);       // 16B chunk of [q][s] row
                *(bf16x4*)&ps[wave][l16][((c ^ (l16 & 7)) << 3) + ((quad & 1) << 2)] = pp;
            }
            bf16x8 af0 = *(const bf16x8*)&ps[wave][l16][SWE(quad, l16)];
            bf16x8 af1 = *(const bf16x8*)&ps[wave][l16][SWE(4 + quad, l16)];
            // O^T += V^T P^T : rows=d (in-lane regs), cols=q (l16)
            #pragma unroll
            for (int ns = 0; ns < 4; ++ns) {
                oacc[qs][ns] = __builtin_amdgcn_mfma_f32_16x16x32_bf16(vf[0][ns], af0, oacc[qs][ns], 0, 0, 0);
                oacc[qs][ns] = __builtin_amdgcn_mfma_f32_16x16x32_bf16(vf[1][ns], af1, oacc[qs][ns], 0, 0, 0);
            }
            lacc[qs] = __builtin_amdgcn_mfma_f32_16x16x32_bf16(ones, af0, lacc[qs], 0, 0, 0);
            lacc[qs] = __builtin_amdgcn_mfma_f32_16x16x32_bf16(ones, af1, lacc[qs], 0, 0, 0);
        }
    }

    // epilogue: per-lane row-sum (col=q=l16), f32x4 stores along d
    #pragma unroll
    for (int qs = 0; qs < 4; ++qs) {
        const float linv = 1.f / (lacc[qs][0] + 1e-8f);
        const int q = qt * 128 + wave * 64 + qs * 16 + l16;
        float* obase = out + ((size_t)b * Ssz + q) * Dsz + h * DKsz;
        #pragma unroll
        for (int ns = 0; ns < 4; ++ns) {
            f32x4 o = oacc[qs][ns] * linv;
            *(f32x4*)(obase + ns * 16 + quad * 4) = o;
        }
    }
}

extern "C" void kernel_launch(void* const* d_in, const int* in_sizes, int n_in,
                              void* d_out, int out_size, void* d_ws, size_t ws_size,
                              hipStream_t stream) {
    const float* x  = (const float*)d_in[0];
    const float* Wq = (const float*)d_in[1];
    const float* Wk = (const float*)d_in[2];
    const float* Wv = (const float*)d_in[3];
    float* out = (float*)d_out;

    const size_t per = (size_t)Bsz * Hsz * Ssz * DKsz;  // 4,194,304 elems
    __bf16* Qw  = (__bf16*)d_ws;
    __bf16* Kw  = Qw + per;
    __bf16* VTw = Kw + per;
    __bf16* xb  = VTw + per;
    __bf16* Wb  = xb + per;                              // 786,432 elems

    cvt_kernel<<<4864, 256, 0, stream>>>(x, Wq, Wk, Wv, xb, Wb);
    qkv_kernel<<<768, 256, 0, stream>>>(xb, Wb, Qw, Kw, VTw);
    attn_kernel<<<dim3(Bsz * Hsz, Ssz / 128), 128, 0, stream>>>(Qw, Kw, VTw, out);
}

// Round 12
// 143.591 us; speedup vs baseline: 1.0906x; 1.0906x over previous
//
#include <hip/hip_runtime.h>
#include <hip/hip_bf16.h>

#define Bsz 4
#define Ssz 2048
#define Dsz 512
#define Hsz 8
#define DKsz 64

typedef __bf16 bf16x8 __attribute__((ext_vector_type(8)));
typedef __bf16 bf16x4 __attribute__((ext_vector_type(4)));
typedef short s16x4 __attribute__((ext_vector_type(4)));
typedef float f32x4 __attribute__((ext_vector_type(4)));

// chunk-swizzled element offset: 16B chunk c of a 64-elem (128B) row, XOR row&7
#define SWE(c, row) ((((c) ^ ((row) & 7)) * 8))

__device__ __forceinline__ s16x4 bc16(bf16x4 v) {
    s16x4 r; __builtin_memcpy(&r, &v, 8); return r;
}

// ---------------------------------------------------------------------------
// cvt: x (4.19M fp32) + Wq|Wk|Wv (3 x 262144 fp32) -> bf16 in ws.
__global__ __launch_bounds__(256) void cvt_kernel(
    const float* __restrict__ x, const float* __restrict__ Wq,
    const float* __restrict__ Wk, const float* __restrict__ Wv,
    __bf16* __restrict__ xb, __bf16* __restrict__ Wb)
{
    const int i = blockIdx.x * 256 + threadIdx.x;   // float4 index
    const int XN4 = (Bsz * Ssz * Dsz) / 4;          // 1,048,576
    const float* src;
    __bf16* dst;
    int off;
    if (i < XN4) {
        src = x; dst = xb; off = i;
    } else {
        int j = i - XN4;                             // 0 .. 196607
        int w = j >> 16;                             // 0,1,2
        off = j & 65535;
        src = (w == 0) ? Wq : (w == 1) ? Wk : Wv;
        dst = Wb + (size_t)w * (Dsz * Dsz);
    }
    float4 v = ((const float4*)src)[off];
    __bf16 o[4] = {(__bf16)v.x, (__bf16)v.y, (__bf16)v.z, (__bf16)v.w};
    *(uint2*)(dst + (size_t)off * 4) = *(uint2*)o;
}

// ---------------------------------------------------------------------------
// Fused qkv projection (R9 structure). L2-locality grid (1-D, 768 blocks):
// XCD = lin&7; 12 time-adjacent blocks per XCD share one x-tile and sweep all
// 12 (tn,which) W-tiles. 128x128 tile, swizzled LDS, reg prefetch, 8B stores.
// which<2 (Q/K): C = W-tile x x-tile -> rows=e (in-lane), cols=s.
// which==2 (V) : C = x-tile x W-tile -> rows=s (in-lane), cols=e -> V^T.
__global__ __launch_bounds__(256, 3) void qkv_kernel(
    const __bf16* __restrict__ xb, const __bf16* __restrict__ Wb,
    __bf16* __restrict__ Qo, __bf16* __restrict__ Ko, __bf16* __restrict__ Vo)
{
    __shared__ __bf16 xs[128][64];
    __shared__ __bf16 wsh[128][64];

    const int tid  = threadIdx.x;
    const int lane = tid & 63;
    const int wave = tid >> 6;
    const int quad = lane >> 4;
    const int l16  = lane & 15;
    const int wm   = (wave & 1) * 64;
    const int wn   = (wave >> 1) * 64;

    const int lin = blockIdx.x;
    const int xcd = lin & 7;
    const int idx = lin >> 3;             // 0..95
    const int tnw = idx % 12;             // fast per XCD: sweeps (tn, which)
    const int tmh = idx / 12;             // slow: x-tile group
    const int tm  = (tmh * 8 + xcd) * 128;
    const int tn  = (tnw & 3) * 128;
    const int which = tnw >> 2;           // 0=Q 1=K 2=V
    const bool VM = (which == 2);
    const __bf16* W = Wb + (size_t)which * (Dsz * Dsz);

    const int srow = tid >> 3;            // 0..31 (+32i covers 128 rows)
    const int sc   = tid & 7;             // 16B chunk within the 128B row
    const int swz  = SWE(sc, srow);       // (srow+32i)&7 == srow&7: i-invariant

    const __bf16* xg = xb + (size_t)(tm + srow) * Dsz + sc * 8;
    const __bf16* wg = W  + (size_t)(tn + srow) * Dsz + sc * 8;

    bf16x8 px[4], pw[4];
    #pragma unroll
    for (int i = 0; i < 4; ++i) {
        px[i] = *(const bf16x8*)(xg + (size_t)(32 * i) * Dsz);
        pw[i] = *(const bf16x8*)(wg + (size_t)(32 * i) * Dsz);
    }

    f32x4 acc[4][4];
    #pragma unroll
    for (int i = 0; i < 4; ++i)
        #pragma unroll
        for (int j = 0; j < 4; ++j) acc[i][j] = (f32x4){0.f, 0.f, 0.f, 0.f};

    const __bf16 (*Ash)[64] = VM ? xs : wsh;
    const __bf16 (*Bsh)[64] = VM ? wsh : xs;

    for (int k0 = 0; k0 < Dsz; k0 += 64) {
        __syncthreads();
        #pragma unroll
        for (int i = 0; i < 4; ++i) {
            *(bf16x8*)&xs[srow + 32 * i][swz]  = px[i];
            *(bf16x8*)&wsh[srow + 32 * i][swz] = pw[i];
        }
        __syncthreads();
        if (k0 + 64 < Dsz) {
            #pragma unroll
            for (int i = 0; i < 4; ++i) {
                px[i] = *(const bf16x8*)(xg + (size_t)(32 * i) * Dsz + k0 + 64);
                pw[i] = *(const bf16x8*)(wg + (size_t)(32 * i) * Dsz + k0 + 64);
            }
        }

        #pragma unroll
        for (int kk = 0; kk < 2; ++kk) {
            bf16x8 fa[4], fb[4];
            #pragma unroll
            for (int mi = 0; mi < 4; ++mi) {
                const int row = wm + mi * 16 + l16;
                fa[mi] = *(const bf16x8*)&Ash[row][SWE(kk * 4 + quad, row)];
            }
            #pragma unroll
            for (int ni = 0; ni < 4; ++ni) {
                const int row = wn + ni * 16 + l16;
                fb[ni] = *(const bf16x8*)&Bsh[row][SWE(kk * 4 + quad, row)];
            }
            #pragma unroll
            for (int mi = 0; mi < 4; ++mi)
                #pragma unroll
                for (int ni = 0; ni < 4; ++ni)
                    acc[mi][ni] = __builtin_amdgcn_mfma_f32_16x16x32_bf16(
                        fa[mi], fb[ni], acc[mi][ni], 0, 0, 0);
        }
    }

    if (!VM) {
        const float scale = (which == 0) ? 0.125f * 1.44269504088896340736f : 1.0f;
        __bf16* dst = (which == 0) ? Qo : Ko;
        // rows = e (W-dim), in-lane regs r span 4 consecutive e -> 4 consecutive d
        #pragma unroll
        for (int mi = 0; mi < 4; ++mi) {
            const int e0 = tn + wm + mi * 16 + quad * 4;
            const int h = e0 >> 6, d0 = e0 & 63;
            #pragma unroll
            for (int ni = 0; ni < 4; ++ni) {
                const int sf = tm + wn + ni * 16 + l16;
                const int b = sf >> 11, s = sf & (Ssz - 1);
                bf16x4 p;
                #pragma unroll
                for (int r = 0; r < 4; ++r) p[r] = (__bf16)(acc[mi][ni][r] * scale);
                *(bf16x4*)&dst[((((size_t)(b * Hsz + h) * Ssz + s)) << 6) + d0] = p;
            }
        }
    } else {
        // rows = s, in-lane regs r span 4 consecutive s -> V^T packed stores
        #pragma unroll
        for (int mi = 0; mi < 4; ++mi) {
            const int sf0 = tm + wm + mi * 16 + quad * 4;
            const int b = sf0 >> 11, s0 = sf0 & (Ssz - 1);
            #pragma unroll
            for (int ni = 0; ni < 4; ++ni) {
                const int e = tn + wn + ni * 16 + l16;
                const int h = e >> 6, d = e & 63;
                bf16x4 p;
                #pragma unroll
                for (int r = 0; r < 4; ++r) p[r] = (__bf16)acc[mi][ni][r];
                *(bf16x4*)&Vo[(((size_t)(b * Hsz + h) * DKsz + d) << 11) + s0] = p;
            }
        }
    }
}

// ---------------------------------------------------------------------------
// Flash attention v3: NO P LDS round-trip. S^T is computed transposed
// (A=K, B=Q, 16x16x32): its C-layout (row = s = quad*4+r, col = q = l16) is
// IDENTICAL to the B-operand fragment layout of v_mfma_f32_16x16x16_bf16
// (B[k=quad*4+j][n=l16]). So P = exp2(S^T) converts in-register to the PV
// B-operand: PV runs as 4x K=16 MFMAs per 64-s tile, A = V^T b64 frags.
// O^T accumulates in regs -> f32x4 stores; row-sums via ones-A K=16 MFMA.
// 4 waves, qs=2 (128 q-rows/block), 2 blocks/CU, XOR-swizzled K/V staging.
__global__ __launch_bounds__(256, 2) void attn_kernel(
    const __bf16* __restrict__ Q, const __bf16* __restrict__ K,
    const __bf16* __restrict__ VT, float* __restrict__ out)
{
    __shared__ __bf16 ks[64][64];        // K[s_local][dk], swizzled chunks
    __shared__ __bf16 vs[64][64];        // V^T[dk][s_local], swizzled chunks

    const int tid  = threadIdx.x;
    const int lane = tid & 63;
    const int wave = tid >> 6;
    const int quad = lane >> 4;
    const int l16  = lane & 15;

    const int bh = blockIdx.x;           // all q-blocks of a bh share an XCD L2
    const int qt = blockIdx.y;           // 128-row q tile
    const int b  = bh >> 3;
    const int h  = bh & 7;

    const __bf16* Qb = Q  + (size_t)bh * Ssz * DKsz;
    const __bf16* Kb = K  + (size_t)bh * Ssz * DKsz;
    const __bf16* Vb = VT + (size_t)bh * DKsz * Ssz;

    // Q fragments: lane l16 = q-local row, quad*8 = dk chunk
    bf16x8 qf[2][2];
    #pragma unroll
    for (int qs = 0; qs < 2; ++qs) {
        const __bf16* qrow = Qb + (size_t)(qt * 128 + wave * 32 + qs * 16 + l16) * DKsz;
        qf[qs][0] = *(const bf16x8*)(qrow + quad * 8);
        qf[qs][1] = *(const bf16x8*)(qrow + 32 + quad * 8);
    }

    s16x4 ones16;
    #pragma unroll
    for (int i = 0; i < 4; ++i) ones16[i] = (short)0x3F80;   // bf16 1.0

    f32x4 oacc[2][4];
    #pragma unroll
    for (int qs = 0; qs < 2; ++qs)
        #pragma unroll
        for (int i = 0; i < 4; ++i) oacc[qs][i] = (f32x4){0.f, 0.f, 0.f, 0.f};
    f32x4 lacc[2] = {(f32x4){0.f, 0.f, 0.f, 0.f}, (f32x4){0.f, 0.f, 0.f, 0.f}};

    const int srow = tid >> 3;           // 0..31 (+32 covers 64 rows)
    const int sc   = tid & 7;            // 16B chunk within the 128B row
    const int swz  = SWE(sc, srow);      // (srow+32)&7 == srow&7

    const __bf16* kg = Kb + (size_t)srow * DKsz + sc * 8;   // K rows = 128B
    const __bf16* vg = Vb + (size_t)srow * Ssz + sc * 8;    // V^T kb-slice

    bf16x8 pk0 = *(const bf16x8*)(kg);
    bf16x8 pk1 = *(const bf16x8*)(kg + (size_t)32 * DKsz);
    bf16x8 pv0 = *(const bf16x8*)(vg);
    bf16x8 pv1 = *(const bf16x8*)(vg + (size_t)32 * Ssz);

    for (int kb = 0; kb < Ssz; kb += 64) {
        __syncthreads();                 // previous tile fully consumed
        *(bf16x8*)&ks[srow][swz]      = pk0;
        *(bf16x8*)&ks[srow + 32][swz] = pk1;
        *(bf16x8*)&vs[srow][swz]      = pv0;
        *(bf16x8*)&vs[srow + 32][swz] = pv1;
        __syncthreads();

        if (kb + 64 < Ssz) {             // prefetch next K/V tile into regs
            pk0 = *(const bf16x8*)(kg + (size_t)(kb + 64) * DKsz);
            pk1 = *(const bf16x8*)(kg + (size_t)(kb + 96) * DKsz);
            pv0 = *(const bf16x8*)(vg + kb + 64);
            pv1 = *(const bf16x8*)(vg + (size_t)32 * Ssz + kb + 64);
        }

        // K frags (B-op of S^T, K=32): 8 b128 reads
        bf16x8 kf[2][4];
        #pragma unroll
        for (int kk = 0; kk < 2; ++kk)
            #pragma unroll
            for (int ns = 0; ns < 4; ++ns) {
                const int row = ns * 16 + l16;
                kf[kk][ns] = *(const bf16x8*)&ks[row][SWE(kk * 4 + quad, row)];
            }
        // V^T frags (A-op of PV, K=16): 16 b64 reads.
        // A[m=d][k=s]: row = ns*16+l16 (d), col = sblk*16 + quad*4 (+j)
        s16x4 vfa[4][4];                 // [sblk][ns]
        #pragma unroll
        for (int sblk = 0; sblk < 4; ++sblk)
            #pragma unroll
            for (int ns = 0; ns < 4; ++ns) {
                const int row = ns * 16 + l16;
                const int c = sblk * 2 + (quad >> 1);
                vfa[sblk][ns] = *(const s16x4*)&vs[row][((c ^ (row & 7)) << 3) + ((quad & 1) << 2)];
            }

        #pragma unroll
        for (int qs = 0; qs < 2; ++qs) {
            // S^T = K Q^T (C: row = s = sblk*16+quad*4+r, col = q = l16);
            // P = exp2(S^T) -> in-register B-frag for K=16 PV MFMAs.
            s16x4 pfr[4];
            #pragma unroll
            for (int sblk = 0; sblk < 4; ++sblk) {
                f32x4 st = (f32x4){0.f, 0.f, 0.f, 0.f};
                st = __builtin_amdgcn_mfma_f32_16x16x32_bf16(kf[0][sblk], qf[qs][0], st, 0, 0, 0);
                st = __builtin_amdgcn_mfma_f32_16x16x32_bf16(kf[1][sblk], qf[qs][1], st, 0, 0, 0);
                bf16x4 pp;
                #pragma unroll
                for (int r = 0; r < 4; ++r)
                    pp[r] = (__bf16)__builtin_amdgcn_exp2f(st[r]);
                pfr[sblk] = bc16(pp);
            }
            // O^T += V^T P^T (K=16): rows=d (in-lane regs), cols=q (l16)
            #pragma unroll
            for (int sblk = 0; sblk < 4; ++sblk) {
                #pragma unroll
                for (int ns = 0; ns < 4; ++ns)
                    oacc[qs][ns] = __builtin_amdgcn_mfma_f32_16x16x16bf16_1k(
                        vfa[sblk][ns], pfr[sblk], oacc[qs][ns], 0, 0, 0);
                lacc[qs] = __builtin_amdgcn_mfma_f32_16x16x16bf16_1k(
                    ones16, pfr[sblk], lacc[qs], 0, 0, 0);
            }
        }
    }

    // epilogue: per-lane row-sum (col=q=l16), f32x4 stores along d
    #pragma unroll
    for (int qs = 0; qs < 2; ++qs) {
        const float linv = 1.f / (lacc[qs][0] + 1e-8f);
        const int q = qt * 128 + wave * 32 + qs * 16 + l16;
        float* obase = out + ((size_t)b * Ssz + q) * Dsz + h * DKsz;
        #pragma unroll
        for (int ns = 0; ns < 4; ++ns) {
            f32x4 o = oacc[qs][ns] * linv;
            *(f32x4*)(obase + ns * 16 + quad * 4) = o;
        }
    }
}

extern "C" void kernel_launch(void* const* d_in, const int* in_sizes, int n_in,
                              void* d_out, int out_size, void* d_ws, size_t ws_size,
                              hipStream_t stream) {
    const float* x  = (const float*)d_in[0];
    const float* Wq = (const float*)d_in[1];
    const float* Wk = (const float*)d_in[2];
    const float* Wv = (const float*)d_in[3];
    float* out = (float*)d_out;

    const size_t per = (size_t)Bsz * Hsz * Ssz * DKsz;  // 4,194,304 elems
    __bf16* Qw  = (__bf16*)d_ws;
    __bf16* Kw  = Qw + per;
    __bf16* VTw = Kw + per;
    __bf16* xb  = VTw + per;
    __bf16* Wb  = xb + per;                              // 786,432 elems

    cvt_kernel<<<4864, 256, 0, stream>>>(x, Wq, Wk, Wv, xb, Wb);
    qkv_kernel<<<768, 256, 0, stream>>>(xb, Wb, Qw, Kw, VTw);
    attn_kernel<<<dim3(Bsz * Hsz, Ssz / 128), 256, 0, stream>>>(Qw, Kw, VTw, out);
}